// Round 1
// baseline (2053.593 us; speedup 1.0000x reference)
//
#include <hip/hip_runtime.h>
#include <math.h>

#define NB 2
#define NL 2048
#define NDIM 1024
#define NH 16
#define ND 64
#define NWS 256
#define NM (NB*NL)
#define SCALE 0.125f

// C[m,n] = sum_k A[m,k]*Bw[n,k] + bias[n]
// MODE 0: scatter into Q/K/V [B,H,L,D] buffers (QKV gemm)
// MODE 1: plain row-major C (proj gemm)
template<int MODE>
__launch_bounds__(256)
__global__ void gemm_bt(const float* __restrict__ A, const float* __restrict__ Bw,
                        const float* __restrict__ bias, float* __restrict__ C,
                        int K, int N,
                        float* __restrict__ qo, float* __restrict__ ko, float* __restrict__ vo)
{
    __shared__ float As[16][64];
    __shared__ float Bs[16][64];
    const int tid = threadIdx.x;
    const int tx = tid & 15, ty = tid >> 4;
    const int m0 = blockIdx.y << 6, n0 = blockIdx.x << 6;
    const int lrow = tid >> 2;          // 0..63
    const int lk   = (tid & 3) << 2;    // 0,4,8,12
    const float* Ap = A + (size_t)(m0 + lrow) * K + lk;
    const float* Bp = Bw + (size_t)(n0 + lrow) * K + lk;
    float acc[4][4] = {};
    for (int k0 = 0; k0 < K; k0 += 16) {
        const float4 av = *(const float4*)(Ap + k0);
        const float4 bv = *(const float4*)(Bp + k0);
        __syncthreads();
        As[lk+0][lrow]=av.x; As[lk+1][lrow]=av.y; As[lk+2][lrow]=av.z; As[lk+3][lrow]=av.w;
        Bs[lk+0][lrow]=bv.x; Bs[lk+1][lrow]=bv.y; Bs[lk+2][lrow]=bv.z; Bs[lk+3][lrow]=bv.w;
        __syncthreads();
        #pragma unroll
        for (int kk = 0; kk < 16; ++kk) {
            const float4 a4 = *(const float4*)&As[kk][ty<<2];
            const float4 b4 = *(const float4*)&Bs[kk][tx<<2];
            const float a[4] = {a4.x,a4.y,a4.z,a4.w};
            const float b[4] = {b4.x,b4.y,b4.z,b4.w};
            #pragma unroll
            for (int i=0;i<4;i++)
                #pragma unroll
                for (int j=0;j<4;j++)
                    acc[i][j] = fmaf(a[i], b[j], acc[i][j]);
        }
    }
    #pragma unroll
    for (int i=0;i<4;i++){
        const int m = m0 + (ty<<2) + i;
        if (MODE == 0) {
            const int bb = m >> 11, l = m & (NL-1);
            #pragma unroll
            for (int j=0;j<4;j++){
                const int n = n0 + (tx<<2) + j;
                const float val = acc[i][j] + bias[n];
                const int sel = n >> 10;     // 0:q 1:k 2:v
                const int hd  = n & 1023;    // h*64+d
                float* dst = (sel==0) ? qo : (sel==1) ? ko : vo;
                dst[(((size_t)(bb*NH + (hd>>6))*NL + l) << 6) + (hd & 63)] = val;
            }
        } else {
            const int n = n0 + (tx<<2);
            float4 v;
            v.x = acc[i][0] + bias[n+0];
            v.y = acc[i][1] + bias[n+1];
            v.z = acc[i][2] + bias[n+2];
            v.w = acc[i][3] + bias[n+3];
            *(float4*)(C + (size_t)m*N + n) = v;
        }
    }
}

// In-place RoPE on Q and K ([B,H,L,D]); one thread handles pair (j, j+32).
__launch_bounds__(256)
__global__ void rope_kernel(float* __restrict__ Q, float* __restrict__ K)
{
    const int idx = blockIdx.x*256 + threadIdx.x;   // NB*NH*NL*32
    const int j  = idx & 31;
    const int l  = (idx >> 5) & (NL-1);
    const int bh = idx >> 16;
    const float invf = 1.0f / powf(10000.0f, (float)j * (1.0f/32.0f));
    const float ang  = (float)l * invf;
    float s, c;
    sincosf(ang, &s, &c);
    const size_t base = (((size_t)bh*NL + l) << 6) + j;
    {
        const float x1 = Q[base], x2 = Q[base+32];
        Q[base]    = x1*c - x2*s;
        Q[base+32] = x2*c + x1*s;
    }
    {
        const float x1 = K[base], x2 = K[base+32];
        K[base]    = x1*c - x2*s;
        K[base+32] = x2*c + x1*s;
    }
}

// Flash attention, fp32. One query row per thread; 256 queries per block.
// Handles is_global (full range) and local windows (WS=256 aligns with block).
__launch_bounds__(256)
__global__ void attn_kernel(const float* __restrict__ Q, const float* __restrict__ K,
                            const float* __restrict__ V, float* __restrict__ AO,
                            const int* __restrict__ isg)
{
    __shared__ float Ks[64][64];
    __shared__ float Vs[64][64];
    const int tid = threadIdx.x;
    const int qt = blockIdx.x & 7;        // L/256 = 8 query tiles
    const int bh = blockIdx.x >> 3;       // b*H + h
    const int qi = (qt << 8) + tid;
    const float* Qp = Q + (((size_t)bh*NL + qi) << 6);
    float q[64];
    #pragma unroll
    for (int d=0; d<64; d+=4) {
        const float4 t = *(const float4*)(Qp + d);
        q[d]=t.x; q[d+1]=t.y; q[d+2]=t.z; q[d+3]=t.w;
    }
    float o[64] = {};
    float mx = -3.0e38f, ls = 0.0f;
    const int gflag = isg[0];
    const int klo = gflag ? 0 : (qt << 8);
    const int khi = gflag ? NL : (klo + NWS);
    const float* Kbase = K + (((size_t)bh*NL) << 6);
    const float* Vbase = V + (((size_t)bh*NL) << 6);
    for (int kt = klo; kt < khi; kt += 64) {
        __syncthreads();
        #pragma unroll
        for (int r=0;r<4;r++){
            const int i = tid + (r << 8);
            const int row = i >> 4;
            const int c4 = (i & 15) << 2;
            *(float4*)&Ks[row][c4] = *(const float4*)(Kbase + ((size_t)(kt+row) << 6) + c4);
            *(float4*)&Vs[row][c4] = *(const float4*)(Vbase + ((size_t)(kt+row) << 6) + c4);
        }
        __syncthreads();
        for (int j=0;j<64;j++){
            float s0=0.f,s1=0.f,s2=0.f,s3=0.f;
            #pragma unroll
            for (int d=0;d<64;d+=4){
                s0 = fmaf(q[d+0], Ks[j][d+0], s0);
                s1 = fmaf(q[d+1], Ks[j][d+1], s1);
                s2 = fmaf(q[d+2], Ks[j][d+2], s2);
                s3 = fmaf(q[d+3], Ks[j][d+3], s3);
            }
            const float s = ((s0+s1)+(s2+s3)) * SCALE;
            if (s <= mx) {
                const float p = __expf(s - mx);
                ls += p;
                #pragma unroll
                for (int d=0;d<64;d++) o[d] = fmaf(p, Vs[j][d], o[d]);
            } else {
                const float r = __expf(mx - s);   // rescale old state; new key has p=1
                ls = fmaf(ls, r, 1.0f);
                #pragma unroll
                for (int d=0;d<64;d++) o[d] = fmaf(o[d], r, Vs[j][d]);
                mx = s;
            }
        }
    }
    const float inv = 1.0f / ls;
    const int bb = bh >> 4, h = bh & 15;
    float* Op = AO + ((size_t)(bb*NL + qi) << 10) + (h << 6);
    #pragma unroll
    for (int d=0; d<64; d+=4){
        float4 t;
        t.x=o[d+0]*inv; t.y=o[d+1]*inv; t.z=o[d+2]*inv; t.w=o[d+3]*inv;
        *(float4*)(Op + d) = t;
    }
}

extern "C" void kernel_launch(void* const* d_in, const int* in_sizes, int n_in,
                              void* d_out, int out_size, void* d_ws, size_t ws_size,
                              hipStream_t stream)
{
    const float* x     = (const float*)d_in[0];
    const float* Wqkv  = (const float*)d_in[1];
    const float* bqkv  = (const float*)d_in[2];
    const float* Wproj = (const float*)d_in[3];
    const float* bproj = (const float*)d_in[4];
    const int*   isg   = (const int*)d_in[5];
    float* out = (float*)d_out;
    float* ws  = (float*)d_ws;

    // Workspace layout (floats): Q | K | V | AO, 4M floats (16MB) each = 64MB
    float* Qb = ws;
    float* Kb = ws + (size_t)4*1024*1024;
    float* Vb = ws + (size_t)8*1024*1024;
    float* AO = ws + (size_t)12*1024*1024;

    // 1) QKV gemm + bias, scattered to [B,H,L,D]
    gemm_bt<0><<<dim3(3*NDIM/64, NM/64), 256, 0, stream>>>(
        x, Wqkv, bqkv, nullptr, NDIM, 3*NDIM, Qb, Kb, Vb);
    // 2) RoPE in-place on Q,K
    rope_kernel<<<(NB*NH*NL*32)/256, 256, 0, stream>>>(Qb, Kb);
    // 3) attention -> AO [B*L, H*D]
    attn_kernel<<<NB*NH*(NL/256), 256, 0, stream>>>(Qb, Kb, Vb, AO, isg);
    // 4) proj gemm + bias -> out
    gemm_bt<1><<<dim3(NDIM/64, NM/64), 256, 0, stream>>>(
        AO, Wproj, bproj, out, NDIM, NDIM, nullptr, nullptr, nullptr);
}

// Round 2
// 767.650 us; speedup vs baseline: 2.6752x; 2.6752x over previous
//
#include <hip/hip_runtime.h>
#include <math.h>

#define NB 2
#define NL 2048
#define NDIM 1024
#define NH 16
#define ND 64
#define NWS 256
#define NM (NB*NL)
#define SCALE 0.125f

typedef __attribute__((ext_vector_type(8))) short short8;
typedef __attribute__((ext_vector_type(4))) float f32x4;
typedef unsigned short ushort_t;
typedef unsigned int uint_t;

static __device__ __forceinline__ ushort_t f2bf(float x){
    uint_t u = __float_as_uint(x);
    uint_t r = (u + 0x7fff + ((u >> 16) & 1)) >> 16;   // RNE
    return (ushort_t)r;
}
static __device__ __forceinline__ float bf2f(ushort_t u){
    return __uint_as_float(((uint_t)u) << 16);
}

// ---------------- fp32 GEMM (unchanged from round 1) ----------------
template<int MODE>
__launch_bounds__(256)
__global__ void gemm_bt(const float* __restrict__ A, const float* __restrict__ Bw,
                        const float* __restrict__ bias, float* __restrict__ C,
                        int K, int N,
                        float* __restrict__ qo, float* __restrict__ ko, float* __restrict__ vo)
{
    __shared__ float As[16][64];
    __shared__ float Bs[16][64];
    const int tid = threadIdx.x;
    const int tx = tid & 15, ty = tid >> 4;
    const int m0 = blockIdx.y << 6, n0 = blockIdx.x << 6;
    const int lrow = tid >> 2;
    const int lk   = (tid & 3) << 2;
    const float* Ap = A + (size_t)(m0 + lrow) * K + lk;
    const float* Bp = Bw + (size_t)(n0 + lrow) * K + lk;
    float acc[4][4] = {};
    for (int k0 = 0; k0 < K; k0 += 16) {
        const float4 av = *(const float4*)(Ap + k0);
        const float4 bv = *(const float4*)(Bp + k0);
        __syncthreads();
        As[lk+0][lrow]=av.x; As[lk+1][lrow]=av.y; As[lk+2][lrow]=av.z; As[lk+3][lrow]=av.w;
        Bs[lk+0][lrow]=bv.x; Bs[lk+1][lrow]=bv.y; Bs[lk+2][lrow]=bv.z; Bs[lk+3][lrow]=bv.w;
        __syncthreads();
        #pragma unroll
        for (int kk = 0; kk < 16; ++kk) {
            const float4 a4 = *(const float4*)&As[kk][ty<<2];
            const float4 b4 = *(const float4*)&Bs[kk][tx<<2];
            const float a[4] = {a4.x,a4.y,a4.z,a4.w};
            const float b[4] = {b4.x,b4.y,b4.z,b4.w};
            #pragma unroll
            for (int i=0;i<4;i++)
                #pragma unroll
                for (int j=0;j<4;j++)
                    acc[i][j] = fmaf(a[i], b[j], acc[i][j]);
        }
    }
    #pragma unroll
    for (int i=0;i<4;i++){
        const int m = m0 + (ty<<2) + i;
        if (MODE == 0) {
            const int bb = m >> 11, l = m & (NL-1);
            #pragma unroll
            for (int j=0;j<4;j++){
                const int n = n0 + (tx<<2) + j;
                const float val = acc[i][j] + bias[n];
                const int sel = n >> 10;
                const int hd  = n & 1023;
                float* dst = (sel==0) ? qo : (sel==1) ? ko : vo;
                dst[(((size_t)(bb*NH + (hd>>6))*NL + l) << 6) + (hd & 63)] = val;
            }
        } else {
            const int n = n0 + (tx<<2);
            float4 v;
            v.x = acc[i][0] + bias[n+0];
            v.y = acc[i][1] + bias[n+1];
            v.z = acc[i][2] + bias[n+2];
            v.w = acc[i][3] + bias[n+3];
            *(float4*)(C + (size_t)m*N + n) = v;
        }
    }
}

// -------- RoPE on Q,K + hi/lo bf16 split of Q,K,V -----------------
__launch_bounds__(256)
__global__ void rope_split(const float* __restrict__ Qf, const float* __restrict__ Kf,
                           const float* __restrict__ Vf,
                           ushort_t* __restrict__ Qh, ushort_t* __restrict__ Ql,
                           ushort_t* __restrict__ Kh, ushort_t* __restrict__ Kl,
                           ushort_t* __restrict__ Vh, ushort_t* __restrict__ Vl)
{
    const int idx = blockIdx.x*256 + threadIdx.x;   // NB*NH*NL*32
    const int j  = idx & 31;
    const int l  = (idx >> 5) & (NL-1);
    const int bh = idx >> 16;
    const float invf = 1.0f / powf(10000.0f, (float)j * (1.0f/32.0f));
    const float ang  = (float)l * invf;
    float s, c;
    sincosf(ang, &s, &c);
    const size_t base = (((size_t)bh*NL + l) << 6) + j;

    #pragma unroll
    for (int which = 0; which < 2; ++which) {
        const float* src = which ? Kf : Qf;
        ushort_t* dh = which ? Kh : Qh;
        ushort_t* dl = which ? Kl : Ql;
        const float x1 = src[base], x2 = src[base+32];
        const float ra = x1*c - x2*s;
        const float rb = x2*c + x1*s;
        ushort_t h;
        h = f2bf(ra); dh[base]    = h; dl[base]    = f2bf(ra - bf2f(h));
        h = f2bf(rb); dh[base+32] = h; dl[base+32] = f2bf(rb - bf2f(h));
    }
    {
        const float v1 = Vf[base], v2 = Vf[base+32];
        ushort_t h;
        h = f2bf(v1); Vh[base]    = h; Vl[base]    = f2bf(v1 - bf2f(h));
        h = f2bf(v2); Vh[base+32] = h; Vl[base+32] = f2bf(v2 - bf2f(h));
    }
}

// ---------------- MFMA flash attention, bf16 hi/lo ----------------
// block = 256 thr = 4 waves; wave handles 32 queries; block = 128 queries of one (b,h)
#define MFMA16(a,b,acc) __builtin_amdgcn_mfma_f32_16x16x32_bf16((a),(b),(acc),0,0,0)

__launch_bounds__(256, 2)
__global__ void attn_mfma(const ushort_t* __restrict__ Qh, const ushort_t* __restrict__ Ql,
                          const ushort_t* __restrict__ Kh, const ushort_t* __restrict__ Kl,
                          const ushort_t* __restrict__ Vh, const ushort_t* __restrict__ Vl,
                          float* __restrict__ AO, const int* __restrict__ isg)
{
    __shared__ __align__(16) ushort_t sKh[64*72];
    __shared__ __align__(16) ushort_t sKl[64*72];
    __shared__ __align__(16) ushort_t sVh[64*72];   // transposed: [d][key]
    __shared__ __align__(16) ushort_t sVl[64*72];
    __shared__ __align__(16) uint_t   sP[4][32*68]; // per-wave, packed (ph|pl<<16)

    const int tid  = threadIdx.x;
    const int wv   = tid >> 6, lane = tid & 63;
    const int quad = lane >> 4, l16 = lane & 15;
    const int bh = blockIdx.x >> 4, qt = blockIdx.x & 15;
    const int q0 = qt*128 + wv*32;

    // Q fragments (A-layout: m=l16, k=quad*8+j+32c), resident for whole kernel
    short8 aqh[2][2], aql[2][2];
    {
        const size_t rb = ((size_t)bh*NL + q0) << 6;
        #pragma unroll
        for (int mt=0; mt<2; ++mt)
            #pragma unroll
            for (int c=0; c<2; ++c) {
                const size_t off = rb + (size_t)((mt*16 + l16) << 6) + quad*8 + c*32;
                aqh[mt][c] = *(const short8*)(Qh + off);
                aql[mt][c] = *(const short8*)(Ql + off);
            }
    }

    f32x4 o[2][4];
    #pragma unroll
    for (int mt=0; mt<2; ++mt)
        #pragma unroll
        for (int dnt=0; dnt<4; ++dnt)
            o[mt][dnt] = (f32x4){0.f,0.f,0.f,0.f};
    float ms[8], ls[8];
    #pragma unroll
    for (int i=0;i<8;++i){ ms[i] = -3.0e38f; ls[i] = 0.f; }

    const int gflag = isg[0];
    const int klo = gflag ? 0 : ((qt >> 1) * NWS);
    const int khi = gflag ? NL : (klo + NWS);
    const size_t kvbase = ((size_t)bh*NL) << 6;

    for (int kt = klo; kt < khi; kt += 64) {
        __syncthreads();
        // ---- stage K rows + V transposed ----
        #pragma unroll
        for (int r=0; r<2; ++r) {
            const int slot = tid + r*256;
            {   // K: 64 rows x 64 bf16, row-major, stride 72
                const int key = slot >> 3, ch = slot & 7;
                const size_t g = kvbase + ((size_t)(kt+key) << 6) + ch*8;
                *(uint4*)&sKh[key*72 + ch*8] = *(const uint4*)(Kh + g);
                *(uint4*)&sKl[key*72 + ch*8] = *(const uint4*)(Kl + g);
            }
            {   // V transposed: sV[d][key], stride 72
                const int key = slot & 63, d0 = (slot >> 6) << 3;
                const size_t g = kvbase + ((size_t)(kt+key) << 6) + d0;
                ushort_t tmp[8];
                *(uint4*)tmp = *(const uint4*)(Vh + g);
                #pragma unroll
                for (int j=0;j<8;++j) sVh[(d0+j)*72 + key] = tmp[j];
                *(uint4*)tmp = *(const uint4*)(Vl + g);
                #pragma unroll
                for (int j=0;j<8;++j) sVl[(d0+j)*72 + key] = tmp[j];
            }
        }
        __syncthreads();

        // ---- S = (Q K^T) * SCALE ----
        float t[2][4][4];
        #pragma unroll
        for (int knt=0; knt<4; ++knt) {
            const int rowb = (knt*16 + l16)*72 + quad*8;
            const short8 kh0 = *(const short8*)&sKh[rowb];
            const short8 kh1 = *(const short8*)&sKh[rowb + 32];
            const short8 kl0 = *(const short8*)&sKl[rowb];
            const short8 kl1 = *(const short8*)&sKl[rowb + 32];
            #pragma unroll
            for (int mt=0; mt<2; ++mt) {
                f32x4 s = (f32x4){0.f,0.f,0.f,0.f};
                s = MFMA16(aqh[mt][0], kh0, s);
                s = MFMA16(aqh[mt][1], kh1, s);
                s = MFMA16(aql[mt][0], kh0, s);
                s = MFMA16(aql[mt][1], kh1, s);
                s = MFMA16(aqh[mt][0], kl0, s);
                s = MFMA16(aqh[mt][1], kl1, s);
                #pragma unroll
                for (int r=0;r<4;++r) t[mt][knt][r] = s[r]*SCALE;
            }
        }

        // ---- online softmax (rows live on lanes quad*4+r; cols on l16) ----
        float rm[8];
        #pragma unroll
        for (int mt=0; mt<2; ++mt)
            #pragma unroll
            for (int r=0;r<4;++r)
                rm[mt*4+r] = fmaxf(fmaxf(t[mt][0][r], t[mt][1][r]),
                                   fmaxf(t[mt][2][r], t[mt][3][r]));
        #pragma unroll
        for (int off=1; off<16; off<<=1)
            #pragma unroll
            for (int i=0;i<8;++i)
                rm[i] = fmaxf(rm[i], __shfl_xor(rm[i], off));
        float al[8];
        #pragma unroll
        for (int i=0;i<8;++i){
            const float mn = fmaxf(ms[i], rm[i]);
            al[i] = __expf(ms[i] - mn);
            ms[i] = mn;
        }
        float rs[8] = {0.f,0.f,0.f,0.f,0.f,0.f,0.f,0.f};
        #pragma unroll
        for (int mt=0; mt<2; ++mt)
            #pragma unroll
            for (int knt=0; knt<4; ++knt)
                #pragma unroll
                for (int r=0;r<4;++r){
                    const float p = __expf(t[mt][knt][r] - ms[mt*4+r]);
                    rs[mt*4+r] += p;
                    const ushort_t ph = f2bf(p);
                    const ushort_t pl = f2bf(p - bf2f(ph));
                    sP[wv][(mt*16 + quad*4 + r)*68 + knt*16 + l16] =
                        (uint_t)ph | ((uint_t)pl << 16);
                }
        #pragma unroll
        for (int off=1; off<16; off<<=1)
            #pragma unroll
            for (int i=0;i<8;++i)
                rs[i] += __shfl_xor(rs[i], off);
        #pragma unroll
        for (int i=0;i<8;++i) ls[i] = ls[i]*al[i] + rs[i];
        #pragma unroll
        for (int mt=0; mt<2; ++mt)
            #pragma unroll
            for (int dnt=0; dnt<4; ++dnt)
                #pragma unroll
                for (int r=0;r<4;++r)
                    o[mt][dnt][r] *= al[mt*4+r];

        // ---- PV: O += P V ----
        short8 vfh[4][2], vfl[4][2];
        #pragma unroll
        for (int dnt=0; dnt<4; ++dnt)
            #pragma unroll
            for (int c=0;c<2;++c) {
                const int a = (dnt*16 + l16)*72 + quad*8 + c*32;
                vfh[dnt][c] = *(const short8*)&sVh[a];
                vfl[dnt][c] = *(const short8*)&sVl[a];
            }
        #pragma unroll
        for (int mt=0; mt<2; ++mt) {
            short8 fph[2], fpl[2];
            #pragma unroll
            for (int c=0;c<2;++c) {
                const uint_t* pw = &sP[wv][(mt*16 + l16)*68 + quad*8 + c*32];
                uint_t w[8];
                *(uint4*)&w[0] = *(const uint4*)pw;
                *(uint4*)&w[4] = *(const uint4*)(pw+4);
                short8 hh, ll;
                #pragma unroll
                for (int j=0;j<8;++j){
                    hh[j] = (short)(w[j] & 0xffffu);
                    ll[j] = (short)(w[j] >> 16);
                }
                fph[c]=hh; fpl[c]=ll;
            }
            #pragma unroll
            for (int dnt=0; dnt<4; ++dnt) {
                f32x4 acc = o[mt][dnt];
                acc = MFMA16(fph[0], vfh[dnt][0], acc);
                acc = MFMA16(fph[1], vfh[dnt][1], acc);
                acc = MFMA16(fpl[0], vfh[dnt][0], acc);
                acc = MFMA16(fpl[1], vfh[dnt][1], acc);
                acc = MFMA16(fph[0], vfl[dnt][0], acc);
                acc = MFMA16(fph[1], vfl[dnt][1], acc);
                o[mt][dnt] = acc;
            }
        }
    }

    // ---- epilogue: AO[b][l][h*64+d] = O / l ----
    const int bb = bh >> 4, hh = bh & 15;
    #pragma unroll
    for (int mt=0; mt<2; ++mt)
        #pragma unroll
        for (int r=0; r<4; ++r) {
            const float inv = 1.0f / ls[mt*4+r];
            const int row = q0 + mt*16 + quad*4 + r;
            float* dst = AO + (((size_t)(bb*NL + row)) << 10) + (hh << 6);
            #pragma unroll
            for (int dnt=0; dnt<4; ++dnt)
                dst[dnt*16 + l16] = o[mt][dnt][r] * inv;
        }
}

extern "C" void kernel_launch(void* const* d_in, const int* in_sizes, int n_in,
                              void* d_out, int out_size, void* d_ws, size_t ws_size,
                              hipStream_t stream)
{
    const float* x     = (const float*)d_in[0];
    const float* Wqkv  = (const float*)d_in[1];
    const float* bqkv  = (const float*)d_in[2];
    const float* Wproj = (const float*)d_in[3];
    const float* bproj = (const float*)d_in[4];
    const int*   isg   = (const int*)d_in[5];
    float* out = (float*)d_out;
    float* ws  = (float*)d_ws;

    const size_t M4 = (size_t)4*1024*1024;
    // fp32: Qf | Kf | Vf  (AO reuses Qf region after rope consumes it)
    float* Qf = ws;
    float* Kf = ws + M4;
    float* Vf = ws + 2*M4;
    float* AO = ws;               // aliases Qf (dead after rope_split)
    ushort_t* us = (ushort_t*)(ws + 3*M4);
    ushort_t* Qh = us;            // each 4M elements (8 MB)
    ushort_t* Ql = us + M4;
    ushort_t* Kh = us + 2*M4;
    ushort_t* Kl = us + 3*M4;
    ushort_t* Vh = us + 4*M4;
    ushort_t* Vl = us + 5*M4;
    // total ws use: 48 MB fp32 + 48 MB bf16 = 96 MB

    gemm_bt<0><<<dim3(3*NDIM/64, NM/64), 256, 0, stream>>>(
        x, Wqkv, bqkv, nullptr, NDIM, 3*NDIM, Qf, Kf, Vf);
    rope_split<<<(NB*NH*NL*32)/256, 256, 0, stream>>>(
        Qf, Kf, Vf, Qh, Ql, Kh, Kl, Vh, Vl);
    attn_mfma<<<NB*NH*(NL/128), 256, 0, stream>>>(
        Qh, Ql, Kh, Kl, Vh, Vl, AO, isg);
    gemm_bt<1><<<dim3(NDIM/64, NM/64), 256, 0, stream>>>(
        AO, Wproj, bproj, out, NDIM, NDIM, nullptr, nullptr, nullptr);
}

// Round 3
// 414.525 us; speedup vs baseline: 4.9541x; 1.8519x over previous
//
#include <hip/hip_runtime.h>
#include <math.h>

#define NB 2
#define NL 2048
#define NDIM 1024
#define NH 16
#define ND 64
#define NWS 256
#define NM (NB*NL)
#define SCALE 0.125f

typedef __attribute__((ext_vector_type(8))) short short8;
typedef __attribute__((ext_vector_type(4))) float f32x4;
typedef unsigned short ushort_t;
typedef unsigned int uint_t;

#define MFMA16(a,b,acc) __builtin_amdgcn_mfma_f32_16x16x32_bf16((a),(b),(acc),0,0,0)

static __device__ __forceinline__ ushort_t f2bf(float x){
    uint_t u = __float_as_uint(x);
    uint_t r = (u + 0x7fff + ((u >> 16) & 1)) >> 16;   // RNE
    return (ushort_t)r;
}
static __device__ __forceinline__ float bf2f(ushort_t u){
    return __uint_as_float(((uint_t)u) << 16);
}

static __device__ __forceinline__ void async_load16(const void* g, void* l){
    __builtin_amdgcn_global_load_lds(
        (const __attribute__((address_space(1))) unsigned int*)g,
        (__attribute__((address_space(3))) unsigned int*)l, 16, 0, 0);
}

// ---------------- fp32 -> bf16 hi/lo split ----------------
__launch_bounds__(256)
__global__ void split_hl(const float* __restrict__ in, ushort_t* __restrict__ oh,
                         ushort_t* __restrict__ ol)
{
    const int i = (blockIdx.x*256 + threadIdx.x)*4;
    const float4 v = *(const float4*)(in + i);
    ushort_t h0=f2bf(v.x), h1=f2bf(v.y), h2=f2bf(v.z), h3=f2bf(v.w);
    ushort4 h4; h4.x=h0; h4.y=h1; h4.z=h2; h4.w=h3;
    ushort4 l4;
    l4.x=f2bf(v.x - bf2f(h0)); l4.y=f2bf(v.y - bf2f(h1));
    l4.z=f2bf(v.z - bf2f(h2)); l4.w=f2bf(v.w - bf2f(h3));
    *(ushort4*)(oh + i) = h4;
    *(ushort4*)(ol + i) = l4;
}

// ---------------- bf16 hi/lo MFMA GEMM ----------------
// C[m,n] = sum_k A[m,k]*B[n,k] + bias[n]  (A: M x K, B: N x K, both row-major)
// MODE 0: QKV gemm — fused RoPE, scatter to Qh/Ql/Kh/Kl/Vh/Vl [B,H,L,D]
// MODE 1: proj gemm — fp32 row-major C
template<int MODE>
__launch_bounds__(256, 2)
__global__ void gemm_hl(const ushort_t* __restrict__ Ah, const ushort_t* __restrict__ Al,
                        const ushort_t* __restrict__ Bh, const ushort_t* __restrict__ Bl,
                        const float* __restrict__ bias,
                        float* __restrict__ Cout,
                        ushort_t* __restrict__ oQh, ushort_t* __restrict__ oQl,
                        ushort_t* __restrict__ oKh, ushort_t* __restrict__ oKl,
                        ushort_t* __restrict__ oVh, ushort_t* __restrict__ oVl)
{
    __shared__ __align__(16) ushort_t sA_h[128*32];
    __shared__ __align__(16) ushort_t sA_l[128*32];
    __shared__ __align__(16) ushort_t sB_h[128*32];
    __shared__ __align__(16) ushort_t sB_l[128*32];

    const int tid  = threadIdx.x;
    const int wv   = tid >> 6, lane = tid & 63;
    const int quad = lane >> 4, l16 = lane & 15;
    const int m0 = blockIdx.y << 7, n0 = blockIdx.x << 7;
    const int wr = wv >> 1, wc = wv & 1;

    // staging: wave wv owns one LDS tile; 16B chunks XOR-swizzled by ((row>>1)&3)
    const ushort_t* gsrc = (wv==0)?Ah:(wv==1)?Al:(wv==2)?Bh:Bl;
    ushort_t* lds_base   = (wv==0)?sA_h:(wv==1)?sA_l:(wv==2)?sB_h:sB_l;
    const int rl = lane >> 2;            // row 0..15 within a pass
    const int cp = lane & 3;             // LDS chunk
    const int cg = cp ^ ((rl >> 1) & 3); // global chunk (pass-invariant)
    const int rowb = (wv < 2) ? m0 : n0;
    const ushort_t* gptr = gsrc + (size_t)(rowb + rl)*NDIM + cg*8;

    f32x4 acc[4][4];
    #pragma unroll
    for (int i=0;i<4;++i)
        #pragma unroll
        for (int j=0;j<4;++j) acc[i][j] = (f32x4){0.f,0.f,0.f,0.f};

    const int swz = (l16 >> 1) & 3;
    const int ac_off = (wr*64 + l16)*32 + ((quad ^ swz) << 3);
    const int bc_off = (wc*64 + l16)*32 + ((quad ^ swz) << 3);

    for (int k0 = 0; k0 < NDIM; k0 += 32) {
        __syncthreads();
        const ushort_t* gp = gptr + k0;
        #pragma unroll
        for (int p=0; p<8; ++p)
            async_load16(gp + (size_t)p*16*NDIM, (char*)lds_base + p*1024);
        __syncthreads();

        short8 ah[4], al[4], bh[4], bl[4];
        #pragma unroll
        for (int t=0;t<4;++t){
            ah[t] = *(const short8*)&sA_h[t*512 + ac_off];
            al[t] = *(const short8*)&sA_l[t*512 + ac_off];
            bh[t] = *(const short8*)&sB_h[t*512 + bc_off];
            bl[t] = *(const short8*)&sB_l[t*512 + bc_off];
        }
        #pragma unroll
        for (int mt=0;mt<4;++mt)
            #pragma unroll
            for (int nt=0;nt<4;++nt){
                f32x4 a = acc[mt][nt];
                a = MFMA16(ah[mt], bh[nt], a);
                a = MFMA16(al[mt], bh[nt], a);
                a = MFMA16(ah[mt], bl[nt], a);
                acc[mt][nt] = a;
            }
    }

    if (MODE == 1) {
        const int colb = n0 + wc*64;
        float bq[4];
        #pragma unroll
        for (int nt=0;nt<4;++nt) bq[nt] = bias[colb + nt*16 + l16];
        #pragma unroll
        for (int mt=0;mt<4;++mt)
            #pragma unroll
            for (int r=0;r<4;++r){
                const int m = m0 + wr*64 + mt*16 + quad*4 + r;
                float* orow = Cout + (size_t)m*NDIM + colb;
                #pragma unroll
                for (int nt=0;nt<4;++nt)
                    orow[nt*16 + l16] = acc[mt][nt][r] + bq[nt];
            }
    } else {
        const int colb = n0 + wc*64;          // 64-aligned -> single (sel, head)
        const int sel  = colb >> 10;          // 0:q 1:k 2:v
        const int head = (colb & 1023) >> 6;
        float bq[4];
        #pragma unroll
        for (int nt=0;nt<4;++nt) bq[nt] = bias[colb + nt*16 + l16];

        if (sel == 2) {
            #pragma unroll
            for (int mt=0;mt<4;++mt)
                #pragma unroll
                for (int r=0;r<4;++r){
                    const int m = m0 + wr*64 + mt*16 + quad*4 + r;
                    const int bb = m >> 11, l = m & (NL-1);
                    const size_t ro = ((size_t)((bb*NH + head)*NL + l)) << 6;
                    #pragma unroll
                    for (int nt=0;nt<4;++nt){
                        const float val = acc[mt][nt][r] + bq[nt];
                        const int d = nt*16 + l16;
                        const ushort_t h = f2bf(val);
                        oVh[ro + d] = h;
                        oVl[ro + d] = f2bf(val - bf2f(h));
                    }
                }
        } else {
            ushort_t* dh = sel ? oKh : oQh;
            ushort_t* dl = sel ? oKl : oQl;
            float invf[2];
            #pragma unroll
            for (int ntp=0;ntp<2;++ntp){
                const int j = ntp*16 + l16;           // 0..31
                invf[ntp] = 1.0f / powf(10000.0f, (float)j * (1.0f/32.0f));
            }
            #pragma unroll
            for (int mt=0;mt<4;++mt)
                #pragma unroll
                for (int r=0;r<4;++r){
                    const int m = m0 + wr*64 + mt*16 + quad*4 + r;
                    const int bb = m >> 11, l = m & (NL-1);
                    const size_t ro = ((size_t)((bb*NH + head)*NL + l)) << 6;
                    #pragma unroll
                    for (int ntp=0;ntp<2;++ntp){
                        float s, c;
                        sincosf((float)l * invf[ntp], &s, &c);
                        const float x1 = acc[mt][ntp  ][r] + bq[ntp];
                        const float x2 = acc[mt][ntp+2][r] + bq[ntp+2];
                        const float ra = x1*c - x2*s;
                        const float rb = x2*c + x1*s;
                        const int d1 = ntp*16 + l16;
                        ushort_t h;
                        h = f2bf(ra); dh[ro + d1]      = h; dl[ro + d1]      = f2bf(ra - bf2f(h));
                        h = f2bf(rb); dh[ro + d1 + 32] = h; dl[ro + d1 + 32] = f2bf(rb - bf2f(h));
                    }
                }
        }
    }
}

// ---------------- MFMA flash attention, bf16 hi/lo ----------------
__launch_bounds__(256, 2)
__global__ void attn_mfma(const ushort_t* __restrict__ Qh, const ushort_t* __restrict__ Ql,
                          const ushort_t* __restrict__ Kh, const ushort_t* __restrict__ Kl,
                          const ushort_t* __restrict__ Vh, const ushort_t* __restrict__ Vl,
                          ushort_t* __restrict__ AOh, ushort_t* __restrict__ AOl,
                          const int* __restrict__ isg)
{
    __shared__ __align__(16) ushort_t sKh[64*72];
    __shared__ __align__(16) ushort_t sKl[64*72];
    __shared__ __align__(16) ushort_t sVh[64*72];   // transposed: [d][key]
    __shared__ __align__(16) ushort_t sVl[64*72];
    __shared__ __align__(16) uint_t   sP[4][32*68]; // per-wave, packed (ph|pl<<16)

    const int tid  = threadIdx.x;
    const int wv   = tid >> 6, lane = tid & 63;
    const int quad = lane >> 4, l16 = lane & 15;
    const int bh = blockIdx.x >> 4, qt = blockIdx.x & 15;
    const int q0 = qt*128 + wv*32;

    short8 aqh[2][2], aql[2][2];
    {
        const size_t rb = ((size_t)bh*NL + q0) << 6;
        #pragma unroll
        for (int mt=0; mt<2; ++mt)
            #pragma unroll
            for (int c=0; c<2; ++c) {
                const size_t off = rb + (size_t)((mt*16 + l16) << 6) + quad*8 + c*32;
                aqh[mt][c] = *(const short8*)(Qh + off);
                aql[mt][c] = *(const short8*)(Ql + off);
            }
    }

    f32x4 o[2][4];
    #pragma unroll
    for (int mt=0; mt<2; ++mt)
        #pragma unroll
        for (int dnt=0; dnt<4; ++dnt)
            o[mt][dnt] = (f32x4){0.f,0.f,0.f,0.f};
    float ms[8], ls[8];
    #pragma unroll
    for (int i=0;i<8;++i){ ms[i] = -3.0e38f; ls[i] = 0.f; }

    const int gflag = isg[0];
    const int klo = gflag ? 0 : ((qt >> 1) * NWS);
    const int khi = gflag ? NL : (klo + NWS);
    const size_t kvbase = ((size_t)bh*NL) << 6;

    for (int kt = klo; kt < khi; kt += 64) {
        __syncthreads();
        #pragma unroll
        for (int r=0; r<2; ++r) {
            const int slot = tid + r*256;
            {
                const int key = slot >> 3, ch = slot & 7;
                const size_t g = kvbase + ((size_t)(kt+key) << 6) + ch*8;
                *(uint4*)&sKh[key*72 + ch*8] = *(const uint4*)(Kh + g);
                *(uint4*)&sKl[key*72 + ch*8] = *(const uint4*)(Kl + g);
            }
            {
                const int key = slot & 63, d0 = (slot >> 6) << 3;
                const size_t g = kvbase + ((size_t)(kt+key) << 6) + d0;
                ushort_t tmp[8];
                *(uint4*)tmp = *(const uint4*)(Vh + g);
                #pragma unroll
                for (int j=0;j<8;++j) sVh[(d0+j)*72 + key] = tmp[j];
                *(uint4*)tmp = *(const uint4*)(Vl + g);
                #pragma unroll
                for (int j=0;j<8;++j) sVl[(d0+j)*72 + key] = tmp[j];
            }
        }
        __syncthreads();

        float t[2][4][4];
        #pragma unroll
        for (int knt=0; knt<4; ++knt) {
            const int rowb = (knt*16 + l16)*72 + quad*8;
            const short8 kh0 = *(const short8*)&sKh[rowb];
            const short8 kh1 = *(const short8*)&sKh[rowb + 32];
            const short8 kl0 = *(const short8*)&sKl[rowb];
            const short8 kl1 = *(const short8*)&sKl[rowb + 32];
            #pragma unroll
            for (int mt=0; mt<2; ++mt) {
                f32x4 s = (f32x4){0.f,0.f,0.f,0.f};
                s = MFMA16(aqh[mt][0], kh0, s);
                s = MFMA16(aqh[mt][1], kh1, s);
                s = MFMA16(aql[mt][0], kh0, s);
                s = MFMA16(aql[mt][1], kh1, s);
                s = MFMA16(aqh[mt][0], kl0, s);
                s = MFMA16(aqh[mt][1], kl1, s);
                #pragma unroll
                for (int r=0;r<4;++r) t[mt][knt][r] = s[r]*SCALE;
            }
        }

        float rm[8];
        #pragma unroll
        for (int mt=0; mt<2; ++mt)
            #pragma unroll
            for (int r=0;r<4;++r)
                rm[mt*4+r] = fmaxf(fmaxf(t[mt][0][r], t[mt][1][r]),
                                   fmaxf(t[mt][2][r], t[mt][3][r]));
        #pragma unroll
        for (int off=1; off<16; off<<=1)
            #pragma unroll
            for (int i=0;i<8;++i)
                rm[i] = fmaxf(rm[i], __shfl_xor(rm[i], off));
        float al[8];
        #pragma unroll
        for (int i=0;i<8;++i){
            const float mn = fmaxf(ms[i], rm[i]);
            al[i] = __expf(ms[i] - mn);
            ms[i] = mn;
        }
        float rs[8] = {0.f,0.f,0.f,0.f,0.f,0.f,0.f,0.f};
        #pragma unroll
        for (int mt=0; mt<2; ++mt)
            #pragma unroll
            for (int knt=0; knt<4; ++knt)
                #pragma unroll
                for (int r=0;r<4;++r){
                    const float p = __expf(t[mt][knt][r] - ms[mt*4+r]);
                    rs[mt*4+r] += p;
                    const ushort_t ph = f2bf(p);
                    const ushort_t pl = f2bf(p - bf2f(ph));
                    sP[wv][(mt*16 + quad*4 + r)*68 + knt*16 + l16] =
                        (uint_t)ph | ((uint_t)pl << 16);
                }
        #pragma unroll
        for (int off=1; off<16; off<<=1)
            #pragma unroll
            for (int i=0;i<8;++i)
                rs[i] += __shfl_xor(rs[i], off);
        #pragma unroll
        for (int i=0;i<8;++i) ls[i] = ls[i]*al[i] + rs[i];
        #pragma unroll
        for (int mt=0; mt<2; ++mt)
            #pragma unroll
            for (int dnt=0; dnt<4; ++dnt)
                #pragma unroll
                for (int r=0;r<4;++r)
                    o[mt][dnt][r] *= al[mt*4+r];

        short8 vfh[4][2], vfl[4][2];
        #pragma unroll
        for (int dnt=0; dnt<4; ++dnt)
            #pragma unroll
            for (int c=0;c<2;++c) {
                const int a = (dnt*16 + l16)*72 + quad*8 + c*32;
                vfh[dnt][c] = *(const short8*)&sVh[a];
                vfl[dnt][c] = *(const short8*)&sVl[a];
            }
        #pragma unroll
        for (int mt=0; mt<2; ++mt) {
            short8 fph[2], fpl[2];
            #pragma unroll
            for (int c=0;c<2;++c) {
                const uint_t* pw = &sP[wv][(mt*16 + l16)*68 + quad*8 + c*32];
                uint_t w[8];
                *(uint4*)&w[0] = *(const uint4*)pw;
                *(uint4*)&w[4] = *(const uint4*)(pw+4);
                short8 hh, ll;
                #pragma unroll
                for (int j=0;j<8;++j){
                    hh[j] = (short)(w[j] & 0xffffu);
                    ll[j] = (short)(w[j] >> 16);
                }
                fph[c]=hh; fpl[c]=ll;
            }
            #pragma unroll
            for (int dnt=0; dnt<4; ++dnt) {
                f32x4 acc = o[mt][dnt];
                acc = MFMA16(fph[0], vfh[dnt][0], acc);
                acc = MFMA16(fph[1], vfh[dnt][1], acc);
                acc = MFMA16(fpl[0], vfh[dnt][0], acc);
                acc = MFMA16(fpl[1], vfh[dnt][1], acc);
                acc = MFMA16(fph[0], vfl[dnt][0], acc);
                acc = MFMA16(fph[1], vfl[dnt][1], acc);
                o[mt][dnt] = acc;
            }
        }
    }

    const int bb = bh >> 4, hh = bh & 15;
    #pragma unroll
    for (int mt=0; mt<2; ++mt)
        #pragma unroll
        for (int r=0; r<4; ++r) {
            const float inv = 1.0f / ls[mt*4+r];
            const int row = q0 + mt*16 + quad*4 + r;
            const size_t ob = (((size_t)(bb*NL + row)) << 10) + (hh << 6);
            #pragma unroll
            for (int dnt=0; dnt<4; ++dnt){
                const float val = o[mt][dnt][r] * inv;
                const ushort_t h = f2bf(val);
                AOh[ob + dnt*16 + l16] = h;
                AOl[ob + dnt*16 + l16] = f2bf(val - bf2f(h));
            }
        }
}

extern "C" void kernel_launch(void* const* d_in, const int* in_sizes, int n_in,
                              void* d_out, int out_size, void* d_ws, size_t ws_size,
                              hipStream_t stream)
{
    const float* x     = (const float*)d_in[0];
    const float* Wqkv  = (const float*)d_in[1];
    const float* bqkv  = (const float*)d_in[2];
    const float* Wproj = (const float*)d_in[3];
    const float* bproj = (const float*)d_in[4];
    const int*   isg   = (const int*)d_in[5];
    float* out = (float*)d_out;
    char* base = (char*)d_ws;

    const size_t MB = 1024*1024;
    ushort_t* Qh = (ushort_t*)(base);
    ushort_t* Ql = (ushort_t*)(base + 8*MB);
    ushort_t* Kh = (ushort_t*)(base + 16*MB);
    ushort_t* Kl = (ushort_t*)(base + 24*MB);
    ushort_t* Vh = (ushort_t*)(base + 32*MB);
    ushort_t* Vl = (ushort_t*)(base + 40*MB);
    ushort_t* xh = (ushort_t*)(base + 48*MB);
    ushort_t* xl = (ushort_t*)(base + 56*MB);
    ushort_t* AOh = xh;                       // alias: xh dead after gemm1
    ushort_t* AOl = xl;
    ushort_t* Wqh = (ushort_t*)(base + 64*MB);
    ushort_t* Wql = (ushort_t*)(base + 64*MB + 6291456);
    ushort_t* Wph = (ushort_t*)(base + 76*MB);
    ushort_t* Wpl = (ushort_t*)(base + 76*MB + 2097152);
    // peak ws use: 80 MB

    split_hl<<<4096, 256, 0, stream>>>(x, xh, xl);        // 4096*1024
    split_hl<<<3072, 256, 0, stream>>>(Wqkv, Wqh, Wql);   // 3072*1024
    split_hl<<<1024, 256, 0, stream>>>(Wproj, Wph, Wpl);  // 1024*1024

    gemm_hl<0><<<dim3(3*NDIM/128, NM/128), 256, 0, stream>>>(
        xh, xl, Wqh, Wql, bqkv, nullptr, Qh, Ql, Kh, Kl, Vh, Vl);

    attn_mfma<<<NB*NH*(NL/128), 256, 0, stream>>>(
        Qh, Ql, Kh, Kl, Vh, Vl, AOh, AOl, isg);

    gemm_hl<1><<<dim3(NDIM/128, NM/128), 256, 0, stream>>>(
        AOh, AOl, Wph, Wpl, bproj, out,
        nullptr, nullptr, nullptr, nullptr, nullptr, nullptr);
}

// Round 4
// 364.384 us; speedup vs baseline: 5.6358x; 1.1376x over previous
//
#include <hip/hip_runtime.h>
#include <math.h>

#define NB 2
#define NL 2048
#define NDIM 1024
#define NH 16
#define ND 64
#define NWS 256
#define NM (NB*NL)
#define SCALE 0.125f

typedef __attribute__((ext_vector_type(8))) short short8;
typedef __attribute__((ext_vector_type(4))) float f32x4;
typedef unsigned short ushort_t;
typedef unsigned int uint_t;

#define MFMA16(a,b,acc) __builtin_amdgcn_mfma_f32_16x16x32_bf16((a),(b),(acc),0,0,0)

static __device__ __forceinline__ ushort_t f2bf(float x){
    uint_t u = __float_as_uint(x);
    uint_t r = (u + 0x7fff + ((u >> 16) & 1)) >> 16;   // RNE
    return (ushort_t)r;
}
static __device__ __forceinline__ float bf2f(ushort_t u){
    return __uint_as_float(((uint_t)u) << 16);
}

static __device__ __forceinline__ void async_load16(const void* g, void* l){
    __builtin_amdgcn_global_load_lds(
        (const __attribute__((address_space(1))) unsigned int*)g,
        (__attribute__((address_space(3))) unsigned int*)l, 16, 0, 0);
}

// ---------------- fp32 -> bf16 hi/lo split ----------------
__launch_bounds__(256)
__global__ void split_hl(const float* __restrict__ in, ushort_t* __restrict__ oh,
                         ushort_t* __restrict__ ol)
{
    const int i = (blockIdx.x*256 + threadIdx.x)*4;
    const float4 v = *(const float4*)(in + i);
    ushort_t h0=f2bf(v.x), h1=f2bf(v.y), h2=f2bf(v.z), h3=f2bf(v.w);
    ushort4 h4; h4.x=h0; h4.y=h1; h4.z=h2; h4.w=h3;
    ushort4 l4;
    l4.x=f2bf(v.x - bf2f(h0)); l4.y=f2bf(v.y - bf2f(h1));
    l4.z=f2bf(v.z - bf2f(h2)); l4.w=f2bf(v.w - bf2f(h3));
    *(ushort4*)(oh + i) = h4;
    *(ushort4*)(ol + i) = l4;
}

// ---------------- rope cos/sin tables [j][l], j<32 ----------------
__launch_bounds__(256)
__global__ void rope_tab(float* __restrict__ tc, float* __restrict__ ts)
{
    const int idx = blockIdx.x*256 + threadIdx.x;   // 32*2048
    const int j = idx >> 11, l = idx & (NL-1);
    const float invf = 1.0f / powf(10000.0f, (float)j * (1.0f/32.0f));
    float s, c;
    sincosf((float)l * invf, &s, &c);
    tc[idx] = c; ts[idx] = s;
}

// ---------------- bf16 hi/lo MFMA GEMM ----------------
// MODE 0: QKV gemm — fused RoPE (tables), Q/K -> [B,H,L,D], V -> transposed [B,H,D,L]
// MODE 1: proj gemm — fp32 row-major C
template<int MODE>
__launch_bounds__(256, 2)
__global__ void gemm_hl(const ushort_t* __restrict__ Ah, const ushort_t* __restrict__ Al,
                        const ushort_t* __restrict__ Bh, const ushort_t* __restrict__ Bl,
                        const float* __restrict__ bias,
                        float* __restrict__ Cout,
                        ushort_t* __restrict__ oQh, ushort_t* __restrict__ oQl,
                        ushort_t* __restrict__ oKh, ushort_t* __restrict__ oKl,
                        ushort_t* __restrict__ oVth, ushort_t* __restrict__ oVtl,
                        const float* __restrict__ tcos, const float* __restrict__ tsin)
{
    __shared__ __align__(16) ushort_t sA_h[128*32];
    __shared__ __align__(16) ushort_t sA_l[128*32];
    __shared__ __align__(16) ushort_t sB_h[128*32];
    __shared__ __align__(16) ushort_t sB_l[128*32];
    __shared__ __align__(16) ushort_t sBounce[(MODE==0) ? 4*64*72 : 4];

    const int tid  = threadIdx.x;
    const int wv   = tid >> 6, lane = tid & 63;
    const int quad = lane >> 4, l16 = lane & 15;
    const int m0 = blockIdx.y << 7, n0 = blockIdx.x << 7;
    const int wr = wv >> 1, wc = wv & 1;

    const ushort_t* gsrc = (wv==0)?Ah:(wv==1)?Al:(wv==2)?Bh:Bl;
    ushort_t* lds_base   = (wv==0)?sA_h:(wv==1)?sA_l:(wv==2)?sB_h:sB_l;
    const int rl = lane >> 2;
    const int cp = lane & 3;
    const int cg = cp ^ ((rl >> 1) & 3);
    const int rowb = (wv < 2) ? m0 : n0;
    const ushort_t* gptr = gsrc + (size_t)(rowb + rl)*NDIM + cg*8;

    f32x4 acc[4][4];
    #pragma unroll
    for (int i=0;i<4;++i)
        #pragma unroll
        for (int j=0;j<4;++j) acc[i][j] = (f32x4){0.f,0.f,0.f,0.f};

    const int swz = (l16 >> 1) & 3;
    const int ac_off = (wr*64 + l16)*32 + ((quad ^ swz) << 3);
    const int bc_off = (wc*64 + l16)*32 + ((quad ^ swz) << 3);

    for (int k0 = 0; k0 < NDIM; k0 += 32) {
        __syncthreads();
        const ushort_t* gp = gptr + k0;
        #pragma unroll
        for (int p=0; p<8; ++p)
            async_load16(gp + (size_t)p*16*NDIM, (char*)lds_base + p*1024);
        __syncthreads();

        short8 ah[4], al[4], bh[4], bl[4];
        #pragma unroll
        for (int t=0;t<4;++t){
            ah[t] = *(const short8*)&sA_h[t*512 + ac_off];
            al[t] = *(const short8*)&sA_l[t*512 + ac_off];
            bh[t] = *(const short8*)&sB_h[t*512 + bc_off];
            bl[t] = *(const short8*)&sB_l[t*512 + bc_off];
        }
        #pragma unroll
        for (int mt=0;mt<4;++mt)
            #pragma unroll
            for (int nt=0;nt<4;++nt){
                f32x4 a = acc[mt][nt];
                a = MFMA16(ah[mt], bh[nt], a);
                a = MFMA16(al[mt], bh[nt], a);
                a = MFMA16(ah[mt], bl[nt], a);
                acc[mt][nt] = a;
            }
    }

    if (MODE == 1) {
        const int colb = n0 + wc*64;
        float bq[4];
        #pragma unroll
        for (int nt=0;nt<4;++nt) bq[nt] = bias[colb + nt*16 + l16];
        #pragma unroll
        for (int mt=0;mt<4;++mt)
            #pragma unroll
            for (int r=0;r<4;++r){
                const int m = m0 + wr*64 + mt*16 + quad*4 + r;
                float* orow = Cout + (size_t)m*NDIM + colb;
                #pragma unroll
                for (int nt=0;nt<4;++nt)
                    orow[nt*16 + l16] = acc[mt][nt][r] + bq[nt];
            }
    } else {
        const int colb = n0 + wc*64;          // 64-aligned -> single (sel, head)
        const int sel  = colb >> 10;          // 0:q 1:k 2:v
        const int head = (colb & 1023) >> 6;
        float bq[4];
        #pragma unroll
        for (int nt=0;nt<4;++nt) bq[nt] = bias[colb + nt*16 + l16];

        if (sel == 2) {
            // V -> transposed global [B,H,D,L] via per-wave LDS bounce
            const int bb = m0 >> 11;
            const int Lb = (m0 & (NL-1)) + wr*64;
            ushort_t* sT = sBounce + wv*(64*72);
            const size_t gb = ((size_t)(bb*NH + head)*ND)*NL + Lb;
            const int drow = lane >> 3, dcol = lane & 7;
            #pragma unroll
            for (int pass=0; pass<2; ++pass){
                #pragma unroll
                for (int mt=0;mt<4;++mt)
                    #pragma unroll
                    for (int nt=0;nt<4;++nt)
                        #pragma unroll
                        for (int r=0;r<4;++r){
                            const float val = acc[mt][nt][r] + bq[nt];
                            const ushort_t h = f2bf(val);
                            const ushort_t w = pass ? f2bf(val - bf2f(h)) : h;
                            sT[(nt*16+l16)*72 + mt*16 + quad*4 + r] = w;
                        }
                ushort_t* gdst = pass ? oVtl : oVth;
                #pragma unroll
                for (int dd=0; dd<8; ++dd){
                    const int d = dd*8 + drow;
                    const uint4 v = *(const uint4*)&sT[d*72 + dcol*8];
                    *(uint4*)(gdst + gb + (size_t)d*NL + dcol*8) = v;
                }
            }
        } else {
            ushort_t* dh = sel ? oKh : oQh;
            ushort_t* dl = sel ? oKl : oQl;
            #pragma unroll
            for (int mt=0;mt<4;++mt)
                #pragma unroll
                for (int r=0;r<4;++r){
                    const int m = m0 + wr*64 + mt*16 + quad*4 + r;
                    const int bb = m >> 11, l = m & (NL-1);
                    const size_t ro = ((size_t)((bb*NH + head)*NL + l)) << 6;
                    #pragma unroll
                    for (int ntp=0;ntp<2;++ntp){
                        const int j = ntp*16 + l16;
                        const float c = tcos[j*NL + l];
                        const float s = tsin[j*NL + l];
                        const float x1 = acc[mt][ntp  ][r] + bq[ntp];
                        const float x2 = acc[mt][ntp+2][r] + bq[ntp+2];
                        const float ra = x1*c - x2*s;
                        const float rb = x2*c + x1*s;
                        const int d1 = ntp*16 + l16;
                        ushort_t h;
                        h = f2bf(ra); dh[ro + d1]      = h; dl[ro + d1]      = f2bf(ra - bf2f(h));
                        h = f2bf(rb); dh[ro + d1 + 32] = h; dl[ro + d1 + 32] = f2bf(rb - bf2f(h));
                    }
                }
        }
    }
}

// ---------------- MFMA flash attention, bf16 hi/lo, S^T form ----------------
// block = 4 waves x 32 queries; K tiles in LDS; V^T frags direct from global (L2)
__launch_bounds__(256, 2)
__global__ void attn_mfma(const ushort_t* __restrict__ Qh, const ushort_t* __restrict__ Ql,
                          const ushort_t* __restrict__ Kh, const ushort_t* __restrict__ Kl,
                          const ushort_t* __restrict__ Vth, const ushort_t* __restrict__ Vtl,
                          ushort_t* __restrict__ AOh, ushort_t* __restrict__ AOl,
                          const int* __restrict__ isg)
{
    __shared__ __align__(16) ushort_t sKh[64*72];
    __shared__ __align__(16) ushort_t sKl[64*72];
    __shared__ __align__(16) uint_t   sP[4][32*68];  // per-wave packed (lo<<16)|hi

    const int tid  = threadIdx.x;
    const int wv   = tid >> 6, lane = tid & 63;
    const int quad = lane >> 4, l16 = lane & 15;
    const int bh = blockIdx.x >> 4, qt = blockIdx.x & 15;
    const int q0 = qt*128 + wv*32;
    uint_t* sPw = sP[wv];

    // Q B-frags (n=query on l16, k=d)
    short8 bqh[2][2], bql[2][2];
    {
        const size_t rb = ((size_t)bh*NL + q0) << 6;
        #pragma unroll
        for (int mt=0; mt<2; ++mt)
            #pragma unroll
            for (int c=0; c<2; ++c) {
                const size_t off = rb + (size_t)((mt*16 + l16) << 6) + quad*8 + c*32;
                bqh[mt][c] = *(const short8*)(Qh + off);
                bql[mt][c] = *(const short8*)(Ql + off);
            }
    }

    f32x4 o[2][4];
    #pragma unroll
    for (int mt=0; mt<2; ++mt)
        #pragma unroll
        for (int dnt=0; dnt<4; ++dnt)
            o[mt][dnt] = (f32x4){0.f,0.f,0.f,0.f};
    float ms[2] = {-3.0e38f, -3.0e38f}, ls[2] = {0.f, 0.f};

    const int gflag = isg[0];
    const int klo = gflag ? 0 : ((qt >> 1) * NWS);
    const int khi = gflag ? NL : (klo + NWS);
    const size_t kvbase = ((size_t)bh*NL) << 6;   // K rows [key][d]
    const size_t vtbase = ((size_t)bh*ND)*NL;     // V^T rows [d][key]

    for (int kt = klo; kt < khi; kt += 64) {
        __syncthreads();
        #pragma unroll
        for (int r2=0; r2<2; ++r2) {
            const int slot = tid + (r2<<8);
            const int row = slot >> 3, ch = slot & 7;
            const size_t g = kvbase + ((size_t)(kt+row) << 6) + ch*8;
            const int off = row*72 + ch*8;
            *(uint4*)&sKh[off] = *(const uint4*)(Kh + g);
            *(uint4*)&sKl[off] = *(const uint4*)(Kl + g);
        }
        __syncthreads();

        // ---- S^T = (K Q^T)*SCALE : rows=key(quad*4+r), cols=query(l16) ----
        float t[2][4][4];
        #pragma unroll
        for (int knt=0; knt<4; ++knt) {
            const int rb = (knt*16 + l16)*72 + quad*8;
            const short8 kh0 = *(const short8*)&sKh[rb];
            const short8 kh1 = *(const short8*)&sKh[rb + 32];
            const short8 kl0 = *(const short8*)&sKl[rb];
            const short8 kl1 = *(const short8*)&sKl[rb + 32];
            #pragma unroll
            for (int mt=0; mt<2; ++mt) {
                f32x4 s = (f32x4){0.f,0.f,0.f,0.f};
                s = MFMA16(kh0, bqh[mt][0], s);
                s = MFMA16(kh1, bqh[mt][1], s);
                s = MFMA16(kh0, bql[mt][0], s);
                s = MFMA16(kh1, bql[mt][1], s);
                s = MFMA16(kl0, bqh[mt][0], s);
                s = MFMA16(kl1, bqh[mt][1], s);
                #pragma unroll
                for (int r=0;r<4;++r) t[mt][knt][r] = s[r]*SCALE;
            }
        }

        // ---- online softmax; query state lives on l16, replicated over quads ----
        float al[2];
        #pragma unroll
        for (int mt=0; mt<2; ++mt) {
            float rm = t[mt][0][0];
            #pragma unroll
            for (int knt=0; knt<4; ++knt)
                #pragma unroll
                for (int r=0;r<4;++r) rm = fmaxf(rm, t[mt][knt][r]);
            rm = fmaxf(rm, __shfl_xor(rm, 16));
            rm = fmaxf(rm, __shfl_xor(rm, 32));
            const float mn = fmaxf(ms[mt], rm);
            al[mt] = __expf(ms[mt] - mn);
            ms[mt] = mn;
        }
        #pragma unroll
        for (int mt=0; mt<2; ++mt) {
            float rs = 0.f;
            #pragma unroll
            for (int knt=0; knt<4; ++knt) {
                uint_t pk[4];
                #pragma unroll
                for (int r=0;r<4;++r) {
                    const float p = __expf(t[mt][knt][r] - ms[mt]);
                    rs += p;
                    const uint_t u = __float_as_uint(p);
                    const float res = p - __uint_as_float(u & 0xffff0000u);
                    pk[r] = __builtin_amdgcn_perm(__float_as_uint(res), u, 0x07060302u);
                }
                *(uint4*)&sPw[(mt*16 + l16)*68 + knt*16 + quad*4] = *(const uint4*)pk;
            }
            rs += __shfl_xor(rs, 16);
            rs += __shfl_xor(rs, 32);
            ls[mt] = ls[mt]*al[mt] + rs;
        }
        // rescale O (rows = quad*4+r) by alpha transported from l16 lanes
        #pragma unroll
        for (int mt=0; mt<2; ++mt)
            #pragma unroll
            for (int r=0;r<4;++r) {
                const float a = __int_as_float(__builtin_amdgcn_ds_bpermute(
                    (quad*4 + r) << 2, __float_as_int(al[mt])));
                #pragma unroll
                for (int dnt=0; dnt<4; ++dnt) o[mt][dnt][r] *= a;
            }

        // ---- P A-frags from sP ----
        short8 fph[2][2], fpl[2][2];
        #pragma unroll
        for (int mt=0; mt<2; ++mt)
            #pragma unroll
            for (int c=0; c<2; ++c) {
                const uint_t* pw = &sPw[(mt*16 + l16)*68 + c*32 + quad*8];
                uint_t w[8];
                *(uint4*)&w[0] = *(const uint4*)pw;
                *(uint4*)&w[4] = *(const uint4*)(pw + 4);
                uint_t h[4], l[4];
                #pragma unroll
                for (int jj=0;jj<4;++jj) {
                    h[jj] = __builtin_amdgcn_perm(w[2*jj+1], w[2*jj], 0x05040100u);
                    l[jj] = __builtin_amdgcn_perm(w[2*jj+1], w[2*jj], 0x07060302u);
                }
                fph[mt][c] = *(const short8*)h;
                fpl[mt][c] = *(const short8*)l;
            }

        // ---- PV: O += P V, V^T B-frags straight from global (L2) ----
        #pragma unroll
        for (int dnt=0; dnt<4; ++dnt) {
            const size_t vg = vtbase + (size_t)(dnt*16 + l16)*NL + kt + quad*8;
            const short8 vh0 = *(const short8*)(Vth + vg);
            const short8 vh1 = *(const short8*)(Vth + vg + 32);
            const short8 vl0 = *(const short8*)(Vtl + vg);
            const short8 vl1 = *(const short8*)(Vtl + vg + 32);
            #pragma unroll
            for (int mt=0; mt<2; ++mt) {
                f32x4 a = o[mt][dnt];
                a = MFMA16(fph[mt][0], vh0, a);
                a = MFMA16(fph[mt][1], vh1, a);
                a = MFMA16(fpl[mt][0], vh0, a);
                a = MFMA16(fpl[mt][1], vh1, a);
                a = MFMA16(fph[mt][0], vl0, a);
                a = MFMA16(fph[mt][1], vl1, a);
                o[mt][dnt] = a;
            }
        }
    }

    // ---- epilogue ----
    const int bb = bh >> 4, hh = bh & 15;
    #pragma unroll
    for (int mt=0; mt<2; ++mt)
        #pragma unroll
        for (int r=0; r<4; ++r) {
            const float lsv = __int_as_float(__builtin_amdgcn_ds_bpermute(
                (quad*4 + r) << 2, __float_as_int(ls[mt])));
            const float inv = 1.0f / lsv;
            const int row = q0 + mt*16 + quad*4 + r;
            const size_t ob = (((size_t)(bb*NL + row)) << 10) + (hh << 6);
            #pragma unroll
            for (int dnt=0; dnt<4; ++dnt) {
                const float val = o[mt][dnt][r] * inv;
                const ushort_t h = f2bf(val);
                AOh[ob + dnt*16 + l16] = h;
                AOl[ob + dnt*16 + l16] = f2bf(val - bf2f(h));
            }
        }
}

extern "C" void kernel_launch(void* const* d_in, const int* in_sizes, int n_in,
                              void* d_out, int out_size, void* d_ws, size_t ws_size,
                              hipStream_t stream)
{
    const float* x     = (const float*)d_in[0];
    const float* Wqkv  = (const float*)d_in[1];
    const float* bqkv  = (const float*)d_in[2];
    const float* Wproj = (const float*)d_in[3];
    const float* bproj = (const float*)d_in[4];
    const int*   isg   = (const int*)d_in[5];
    float* out = (float*)d_out;
    char* base = (char*)d_ws;

    const size_t MB = 1024*1024;
    ushort_t* Qh  = (ushort_t*)(base);
    ushort_t* Ql  = (ushort_t*)(base + 8*MB);
    ushort_t* Kh  = (ushort_t*)(base + 16*MB);
    ushort_t* Kl  = (ushort_t*)(base + 24*MB);
    ushort_t* Vth = (ushort_t*)(base + 32*MB);
    ushort_t* Vtl = (ushort_t*)(base + 40*MB);
    ushort_t* xh  = (ushort_t*)(base + 48*MB);
    ushort_t* xl  = (ushort_t*)(base + 56*MB);
    ushort_t* AOh = xh;                       // alias: xh dead after gemm1
    ushort_t* AOl = xl;
    ushort_t* Wqh = (ushort_t*)(base + 64*MB);
    ushort_t* Wql = (ushort_t*)(base + 64*MB + 6291456);
    ushort_t* Wph = (ushort_t*)(base + 76*MB);
    ushort_t* Wpl = (ushort_t*)(base + 76*MB + 2097152);
    float*    tcs = (float*)(base + 80*MB);          // 32*2048 f32
    float*    tsn = (float*)(base + 80*MB + 262144);
    // peak ws use: ~80.5 MB

    split_hl<<<4096, 256, 0, stream>>>(x, xh, xl);
    split_hl<<<3072, 256, 0, stream>>>(Wqkv, Wqh, Wql);
    split_hl<<<1024, 256, 0, stream>>>(Wproj, Wph, Wpl);
    rope_tab<<<256, 256, 0, stream>>>(tcs, tsn);

    gemm_hl<0><<<dim3(3*NDIM/128, NM/128), 256, 0, stream>>>(
        xh, xl, Wqh, Wql, bqkv, nullptr,
        Qh, Ql, Kh, Kl, Vth, Vtl, tcs, tsn);

    attn_mfma<<<NB*NH*(NL/128), 256, 0, stream>>>(
        Qh, Ql, Kh, Kl, Vth, Vtl, AOh, AOl, isg);

    gemm_hl<1><<<dim3(NDIM/128, NM/128), 256, 0, stream>>>(
        AOh, AOl, Wph, Wpl, bproj, out,
        nullptr, nullptr, nullptr, nullptr, nullptr, nullptr, nullptr, nullptr);
}